// Round 10
// baseline (1051.933 us; speedup 1.0000x reference)
//
#include <hip/hip_runtime.h>

typedef __attribute__((ext_vector_type(8))) _Float16 f16x8;
typedef __attribute__((ext_vector_type(4))) _Float16 f16x4;
typedef __attribute__((ext_vector_type(4))) float f32x4;

#define NB 4
#define NS 4096
#define NE 512

__device__ __forceinline__ f16x8 cvt2(float4 a, float4 b) {
    f16x8 r;
    r[0] = (_Float16)a.x; r[1] = (_Float16)a.y; r[2] = (_Float16)a.z; r[3] = (_Float16)a.w;
    r[4] = (_Float16)b.x; r[5] = (_Float16)b.y; r[6] = (_Float16)b.z; r[7] = (_Float16)b.w;
    return r;
}
__device__ __forceinline__ void gload_lds16(const void* g, void* l) {
    __builtin_amdgcn_global_load_lds(
        (const __attribute__((address_space(1))) void*)g,
        (__attribute__((address_space(3))) void*)l, 16, 0, 0);
}

// DPP ring reductions over the 16-lane row (pure VALU, no DS latency).
template <int CTRL>
__device__ __forceinline__ float dpp_ror(float x) {
    int r = __builtin_amdgcn_update_dpp(
        0, __builtin_bit_cast(int, x), CTRL, 0xF, 0xF, true);
    return __builtin_bit_cast(float, r);
}
__device__ __forceinline__ float rmax16(float x) {
    x = fmaxf(x, dpp_ror<0x128>(x));   // row_ror:8
    x = fmaxf(x, dpp_ror<0x124>(x));   // row_ror:4
    x = fmaxf(x, dpp_ror<0x122>(x));   // row_ror:2
    x = fmaxf(x, dpp_ror<0x121>(x));   // row_ror:1
    return x;
}
__device__ __forceinline__ float rsum16(float x) {
    x += dpp_ror<0x128>(x);
    x += dpp_ror<0x124>(x);
    x += dpp_ror<0x122>(x);
    x += dpp_ror<0x121>(x);
    return x;
}

// ---------------- Stage 1: fused QKV projection (fp32 in, f16 out) ------
// v12 (kept): raw-barrier pipelined staging, LDS double-buffer, register
// ping-pong, ONE barrier per K-tile, counted waits.
// q: natural [row][e]. k: swizzled rows — element (s,e) at s*512 + ((e/8)^(s&7))*8 + e%8.
// v: chunked+swizzled [b][kc][e][64]: (d,s) at ((b*64+kc)*512+d)*64 + (((s&63)/8)^(d&7))*8 + s%8.
__global__ __launch_bounds__(256, 2) void proj_kernel(
    const float* __restrict__ Xq, const float* __restrict__ Xk,
    const float* __restrict__ Xv,
    const float* __restrict__ Wq, const float* __restrict__ Wk,
    const float* __restrict__ Wv,
    const float* __restrict__ bq, const float* __restrict__ bk,
    const float* __restrict__ bv,
    _Float16* __restrict__ oq, _Float16* __restrict__ ok,
    _Float16* __restrict__ ovt, int b0)
{
    __shared__ __align__(16) _Float16 As[2][128 * 32];
    __shared__ __align__(16) _Float16 Bs[2][128 * 32];
    const int t = threadIdx.x;
    const int w = t >> 6, ln = t & 63;
    const int which = blockIdx.y;
    const float* X    = (which == 0) ? Xq : ((which == 1) ? Xk : Xv);
    const float* W    = (which == 0) ? Wq : ((which == 1) ? Wk : Wv);
    const float* bias = (which == 0) ? bq : ((which == 1) ? bk : bv);

    const int m0 = (blockIdx.x >> 2) * 128;
    const int n0 = (blockIdx.x & 3) * 128;

    const int srow  = t >> 1;
    const int shalf = (t & 1) * 16;
    const float* gA = X + ((size_t)b0 * NS + m0 + srow) * NE + shalf;
    const float* gB = W + (size_t)(n0 + srow) * NE + shalf;

    f32x4 acc[4][4] = {};
    const int wm = (w >> 1) * 64, wn = (w & 1) * 64;
    const int lcol = ln & 15, lq = ln >> 4;

    float4 ra[4], rb[4], na[4], nb[4];

    auto LOAD = [&](int k0, float4* da, float4* db) {
        da[0] = *(const float4*)(gA + k0);
        da[1] = *(const float4*)(gA + k0 + 4);
        da[2] = *(const float4*)(gA + k0 + 8);
        da[3] = *(const float4*)(gA + k0 + 12);
        db[0] = *(const float4*)(gB + k0);
        db[1] = *(const float4*)(gB + k0 + 4);
        db[2] = *(const float4*)(gB + k0 + 8);
        db[3] = *(const float4*)(gB + k0 + 12);
    };
    auto WRITE = [&](int p, const float4* da, const float4* db) {
        *(f16x8*)&As[p][srow * 32 + shalf]     = cvt2(da[0], da[1]);
        *(f16x8*)&As[p][srow * 32 + shalf + 8] = cvt2(da[2], da[3]);
        *(f16x8*)&Bs[p][srow * 32 + shalf]     = cvt2(db[0], db[1]);
        *(f16x8*)&Bs[p][srow * 32 + shalf + 8] = cvt2(db[2], db[3]);
    };
    auto COMPUTE = [&](int p) {
        f16x8 a[4], b[4];
#pragma unroll
        for (int i = 0; i < 4; i++)
            a[i] = *(const f16x8*)&As[p][(wm + i * 16 + lcol) * 32 + lq * 8];
#pragma unroll
        for (int j = 0; j < 4; j++)
            b[j] = *(const f16x8*)&Bs[p][(wn + j * 16 + lcol) * 32 + lq * 8];
#pragma unroll
        for (int i = 0; i < 4; i++)
#pragma unroll
            for (int j = 0; j < 4; j++)
                acc[i][j] = __builtin_amdgcn_mfma_f32_16x16x32_f16(a[i], b[j], acc[i][j], 0, 0, 0);
    };

    // prologue: tile0 -> buf0, tile1 -> na (in flight)
    LOAD(0, ra, rb);
    asm volatile("s_waitcnt vmcnt(0)" ::: "memory");
    WRITE(0, ra, rb);
    LOAD(32, na, nb);
    asm volatile("s_waitcnt lgkmcnt(0)" ::: "memory");
    __builtin_amdgcn_s_barrier();                   // buf0 visible
    asm volatile("" ::: "memory");

#pragma unroll
    for (int kk = 0; kk < 8; kk++) {
        // ---- tile 2kk from buf0; stage 2kk+1 (na) -> buf1; load 2kk+2 -> ra
        COMPUTE(0);
        asm volatile("s_waitcnt vmcnt(0)" ::: "memory");   // na ready (hidden)
        WRITE(1, na, nb);
        if (2 * kk + 2 < 16) LOAD((2 * kk + 2) * 32, ra, rb);
        asm volatile("s_waitcnt lgkmcnt(0)" ::: "memory");
        __builtin_amdgcn_s_barrier();               // buf1 visible, buf0 free
        asm volatile("" ::: "memory");
        // ---- tile 2kk+1 from buf1; stage 2kk+2 (ra) -> buf0; load 2kk+3 -> na
        COMPUTE(1);
        if (2 * kk + 2 < 16) {
            asm volatile("s_waitcnt vmcnt(0)" ::: "memory");
            WRITE(0, ra, rb);
            if (2 * kk + 3 < 16) LOAD((2 * kk + 3) * 32, na, nb);
            asm volatile("s_waitcnt lgkmcnt(0)" ::: "memory");
            __builtin_amdgcn_s_barrier();           // buf0 visible, buf1 free
            asm volatile("" ::: "memory");
        }
    }

    // C/D layout: col = lane&15, row = (lane>>4)*4 + reg
    if (which == 0) {
#pragma unroll
        for (int j = 0; j < 4; j++) {
            const int col = n0 + wn + j * 16 + lcol;
            const float bb = bias[col];
#pragma unroll
            for (int i = 0; i < 4; i++) {
                const int rbase = m0 + wm + i * 16 + lq * 4;
#pragma unroll
                for (int r = 0; r < 4; r++)
                    oq[(size_t)(rbase + r) * NE + col] = (_Float16)(acc[i][j][r] + bb);
            }
        }
    } else if (which == 1) {
#pragma unroll
        for (int j = 0; j < 4; j++) {
            const int col = n0 + wn + j * 16 + lcol;
            const int cch = col >> 3, clo = col & 7;
            const float bb = bias[col];
#pragma unroll
            for (int i = 0; i < 4; i++) {
                const int rbase = m0 + wm + i * 16 + lq * 4;
#pragma unroll
                for (int r = 0; r < 4; r++) {
                    const int s = rbase + r;
                    ok[(size_t)s * NE + ((cch ^ (s & 7)) << 3) + clo] =
                        (_Float16)(acc[i][j][r] + bb);
                }
            }
        }
    } else {
#pragma unroll
        for (int j = 0; j < 4; j++) {
            const int d = n0 + wn + j * 16 + lcol;
            const float bb = bias[d];
#pragma unroll
            for (int i = 0; i < 4; i++) {
                const int rbase = m0 + wm + i * 16 + lq * 4;
                const int bat = rbase >> 12;
                const int sl  = rbase & 4095;
                const int kc  = sl >> 6;
                const int slot = ((sl >> 3) & 7) ^ (d & 7);
                f16x4 pk;
#pragma unroll
                for (int r = 0; r < 4; r++) pk[r] = (_Float16)(acc[i][j][r] + bb);
                *(f16x4*)&ovt[(((size_t)bat * 64 + kc) * NE + d) * 64 + slot * 8 + (sl & 7)] = pk;
            }
        }
    }
}

// ---------------- Stage 2: flash attention v13 --------------------------
// v10 skeleton (KB=64, 8 waves, 64 iters, split staging, counted vmcnt,
// DPP softmax, folded-max) with PV RE-SPLIT to kill the 4x V-read
// redundancy: wave w now owns E-slice [w*64, w*64+64) across ALL 64 q-rows.
// Each V fragment is read ONCE block-wide and reused across 4 row-tiles in
// registers (V LDS reads 256->64 KB/iter). Every thread tracks m/l state
// for its 16 rows (static-indexed arrays; m_home mirrors the wave's home
// row-tile for the QK fold).
// QK unchanged: wave (rt=w&3, g=w>>2): rows rt*16.., keys g*32..
__global__ __launch_bounds__(512, 2) void attn_kernel(
    const _Float16* __restrict__ q, const _Float16* __restrict__ ksw,
    const _Float16* __restrict__ vsw, float* __restrict__ out, int b0)
{
    __shared__ __align__(16) _Float16 Kb[64 * 512];
    __shared__ __align__(16) _Float16 Vb[512 * 64];
    __shared__ __align__(16) _Float16 Pb[64 * 72];
    __shared__ float mpart[2][64];
    __shared__ float lpart[2][64];

    const int t = threadIdx.x, w = t >> 6, ln = t & 63;
    const int lcol = ln & 15, lq = ln >> 4;
    const int rt = w & 3, g = w >> 2;
    const int xm = lcol & 7;

    // XCD-aware swizzle (proven: FETCH 139->41 MB): 2 XCDs per batch
    int qx, rel;
    if (gridDim.y == 4) {
        const int id = blockIdx.x + (blockIdx.y << 6);   // 0..255, hw xcd = id&7
        const int xcd = id & 7, slot = id >> 3;          // slot 0..31
        rel = xcd >> 1;
        qx  = ((xcd & 1) << 5) + slot;
    } else { qx = blockIdx.x; rel = blockIdx.y; }
    const int babs = b0 + rel;
    const int q0 = qx * 64;

    const _Float16* qp = q + ((size_t)rel * NS + q0 + rt * 16 + lcol) * NE + lq * 8;
    f16x8 qf[16];
#pragma unroll
    for (int ks = 0; ks < 16; ks++) qf[ks] = *(const f16x8*)(qp + ks * 32);

    const _Float16* kbase = ksw + (size_t)rel * NS * NE;
    const _Float16* vbase = vsw + (size_t)rel * NS * NE;

    auto stageK = [&](int kc) {
        const _Float16* src = kbase + (size_t)kc * 64 * NE;
#pragma unroll
        for (int i = 0; i < 8; i++) {
            const int blk = i * 8 + w;                   // 1 KB block index
            gload_lds16(src + (size_t)blk * 512 + ln * 8, (_Float16*)Kb + blk * 512);
        }
    };
    auto stageV = [&](int kc) {
        const _Float16* src = vbase + (size_t)kc * NE * 64;
#pragma unroll
        for (int i = 0; i < 8; i++) {
            const int blk = i * 8 + w;
            gload_lds16(src + (size_t)blk * 512 + ln * 8, (_Float16*)Vb + blk * 512);
        }
    };

    // oacc[qt][et]: row-tile qt (rows qt*16..), col w*64 + et*16
    f32x4 oacc[4][4] = {};
    // per-thread state for rows qt*16 + lq*4 + r (all 64 rows covered)
    float m_st[4][4], l_st[4][4];
#pragma unroll
    for (int qt = 0; qt < 4; qt++)
#pragma unroll
        for (int r = 0; r < 4; r++) { m_st[qt][r] = -1e30f; l_st[qt][r] = 0.f; }
    // mirror of m_st[rt][*] (home row-tile) for the QK fold — static regs
    float m_home[4] = {-1e30f, -1e30f, -1e30f, -1e30f};

    asm volatile("" ::: "memory");
    stageK(0);
    stageV(0);

    for (int kc = 0; kc < 64; kc++) {
        // K(t) done (V(t) / K(t+1) stay in flight); then cross-wave sync
        asm volatile("s_waitcnt vmcnt(8)" ::: "memory");
        __builtin_amdgcn_s_barrier();                    // A: K(t) visible
        asm volatile("" ::: "memory");

        // ---- QK^T: 16 q-rows x 32 keys (keys g*32..+32), K=512
        f32x4 s0 = {}, s1 = {};
        __builtin_amdgcn_s_setprio(1);
#pragma unroll
        for (int ks = 0; ks < 16; ks++) {
            const int ch = ((ks * 4 + lq) ^ xm) * 8;
            f16x8 kb0 = *(const f16x8*)&Kb[(g * 32 + lcol) * 512 + ch];
            f16x8 kb1 = *(const f16x8*)&Kb[(g * 32 + 16 + lcol) * 512 + ch];
            s0 = __builtin_amdgcn_mfma_f32_16x16x32_f16(qf[ks], kb0, s0, 0, 0, 0);
            s1 = __builtin_amdgcn_mfma_f32_16x16x32_f16(qf[ks], kb1, s1, 0, 0, 0);
        }
        __builtin_amdgcn_s_setprio(0);

        asm volatile("" ::: "memory");
        __builtin_amdgcn_s_barrier();                    // B: Kb free
        asm volatile("" ::: "memory");
        if (kc < 63) stageK(kc + 1);                     // overlaps softmax+PV

        // ---- wave-local folded softmax (home rows rt*16 + lq*4+r)
#pragma unroll
        for (int r = 0; r < 4; r++) {
            float mx = rmax16(fmaxf(s0[r], s1[r]));
            const float mg = fmaxf(m_home[r], mx);
            const float p0 = __expf(s0[r] - mg);
            const float p1 = __expf(s1[r] - mg);
            const int row = rt * 16 + lq * 4 + r;
            Pb[row * 72 + g * 32 + lcol]      = (_Float16)p0;
            Pb[row * 72 + g * 32 + 16 + lcol] = (_Float16)p1;
            const float ls = rsum16(p0 + p1);
            if (lcol == 0) { mpart[g][row] = mg; lpart[g][row] = ls; }
        }

        // V(t) done + own P/partial writes visible; then sync
        if (kc < 63) { asm volatile("s_waitcnt vmcnt(8) lgkmcnt(0)" ::: "memory"); }
        else         { asm volatile("s_waitcnt vmcnt(0) lgkmcnt(0)" ::: "memory"); }
        __builtin_amdgcn_s_barrier();                    // C: V(t), P, partials
        asm volatile("" ::: "memory");

        // ---- combine halves for ALL 16 thread-rows; update running state
        float alpha[4][4];
        bool allone = true;
#pragma unroll
        for (int qt = 0; qt < 4; qt++) {
#pragma unroll
            for (int r = 0; r < 4; r++) {
                const int row = qt * 16 + lq * 4 + r;
                const float M0 = mpart[0][row], M1 = mpart[1][row];
                const float mn = fmaxf(M0, M1);
                const float a = __expf(m_st[qt][r] - mn);
                l_st[qt][r] = l_st[qt][r] * a
                            + __expf(M0 - mn) * lpart[0][row]
                            + __expf(M1 - mn) * lpart[1][row];
                m_st[qt][r] = mn;
                if (qt == rt) m_home[r] = mn;            // predicated, static idx
                alpha[qt][r] = a;
                allone = allone & (a == 1.f);
            }
        }
        if (!__all(allone)) {
#pragma unroll
            for (int qt = 0; qt < 4; qt++)
#pragma unroll
                for (int et = 0; et < 4; et++) {
                    oacc[qt][et][0] *= alpha[qt][0];
                    oacc[qt][et][1] *= alpha[qt][1];
                    oacc[qt][et][2] *= alpha[qt][2];
                    oacc[qt][et][3] *= alpha[qt][3];
                }
        }

        // ---- P A-fragments for all 4 row-tiles (rows = lcol within tile)
        // pa0 = keys 0..31 (written by g=0), pa1 = keys 32..63 (g=1);
        // per-half correction exp(Mg - mn) exactly as v10.
        f16x8 pa0[4], pa1[4];
#pragma unroll
        for (int qt = 0; qt < 4; qt++) {
            const int frow = qt * 16 + lcol;
            const float F0 = mpart[0][frow], F1 = mpart[1][frow];
            const float fm = fmaxf(F0, F1);
            const _Float16 c0 = (_Float16)__expf(F0 - fm);
            const _Float16 c1 = (_Float16)__expf(F1 - fm);
            pa0[qt] = *(const f16x8*)&Pb[frow * 72 + lq * 8];
            pa1[qt] = *(const f16x8*)&Pb[frow * 72 + 32 + lq * 8];
#pragma unroll
            for (int j = 0; j < 8; j++) { pa0[qt][j] *= c0; pa1[qt][j] *= c1; }
        }

        // ---- PV: E-slice w*64..+64, ALL 64 rows, K=64.
        // V fragment loaded once per et, reused across 4 row-tiles.
        __builtin_amdgcn_s_setprio(1);
#pragma unroll
        for (int et = 0; et < 4; et++) {
            const int e = w * 64 + et * 16 + lcol;
            f16x8 v0 = *(const f16x8*)&Vb[e * 64 + ((lq ^ xm) * 8)];
            f16x8 v1 = *(const f16x8*)&Vb[e * 64 + (((4 + lq) ^ xm) * 8)];
#pragma unroll
            for (int qt = 0; qt < 4; qt++) {
                oacc[qt][et] = __builtin_amdgcn_mfma_f32_16x16x32_f16(pa0[qt], v0, oacc[qt][et], 0, 0, 0);
                oacc[qt][et] = __builtin_amdgcn_mfma_f32_16x16x32_f16(pa1[qt], v1, oacc[qt][et], 0, 0, 0);
            }
        }
        __builtin_amdgcn_s_setprio(0);

        asm volatile("" ::: "memory");
        __builtin_amdgcn_s_barrier();                    // D: Vb, Pb free
        asm volatile("" ::: "memory");
        if (kc < 63) stageV(kc + 1);                     // overlaps next QK
    }

    // ---- epilogue: wave writes E-slice w*64..+64 for all 64 rows
#pragma unroll
    for (int qt = 0; qt < 4; qt++)
#pragma unroll
        for (int r = 0; r < 4; r++) {
            const float inv = 1.0f / l_st[qt][r];
            const size_t ob = ((size_t)babs * NS + q0 + qt * 16 + lq * 4 + r) * NE
                            + w * 64 + lcol;
#pragma unroll
            for (int et = 0; et < 4; et++)
                out[ob + et * 16] = oacc[qt][et][r] * inv;
        }
}

extern "C" void kernel_launch(void* const* d_in, const int* in_sizes, int n_in,
                              void* d_out, int out_size, void* d_ws, size_t ws_size,
                              hipStream_t stream) {
    const float* query = (const float*)d_in[0];
    const float* key_  = (const float*)d_in[1];
    const float* value = (const float*)d_in[2];
    const float* Wq    = (const float*)d_in[3];
    const float* bq    = (const float*)d_in[4];
    const float* Wk    = (const float*)d_in[5];
    const float* bk    = (const float*)d_in[6];
    const float* Wv    = (const float*)d_in[7];
    const float* bv    = (const float*)d_in[8];

    const size_t per_batch = (size_t)3 * NS * NE * 2;   // q + k_sw + v_sw f16 = 12 MiB
    int nb_chunk = (int)(ws_size / per_batch);
    if (nb_chunk > NB) nb_chunk = NB;
    if (nb_chunk < 1)  nb_chunk = 1;

    _Float16* qh  = (_Float16*)d_ws;
    _Float16* kh  = qh + (size_t)nb_chunk * NS * NE;
    _Float16* vth = kh + (size_t)nb_chunk * NS * NE;

    for (int b0 = 0; b0 < NB; b0 += nb_chunk) {
        int nb = NB - b0 < nb_chunk ? NB - b0 : nb_chunk;
        proj_kernel<<<dim3(nb * 128, 3, 1), 256, 0, stream>>>(
            query, key_, value, Wq, Wk, Wv, bq, bk, bv, qh, kh, vth, b0);
        attn_kernel<<<dim3(NS / 64, nb, 1), 512, 0, stream>>>(
            qh, kh, vth, (float*)d_out, b0);
    }
}

// Round 11
// 460.686 us; speedup vs baseline: 2.2834x; 2.2834x over previous
//
#include <hip/hip_runtime.h>

typedef __attribute__((ext_vector_type(8))) _Float16 f16x8;
typedef __attribute__((ext_vector_type(4))) _Float16 f16x4;
typedef __attribute__((ext_vector_type(4))) float f32x4;

#define NB 4
#define NS 4096
#define NE 512

__device__ __forceinline__ f16x8 cvt2(float4 a, float4 b) {
    f16x8 r;
    r[0] = (_Float16)a.x; r[1] = (_Float16)a.y; r[2] = (_Float16)a.z; r[3] = (_Float16)a.w;
    r[4] = (_Float16)b.x; r[5] = (_Float16)b.y; r[6] = (_Float16)b.z; r[7] = (_Float16)b.w;
    return r;
}
__device__ __forceinline__ void gload_lds16(const void* g, void* l) {
    __builtin_amdgcn_global_load_lds(
        (const __attribute__((address_space(1))) void*)g,
        (__attribute__((address_space(3))) void*)l, 16, 0, 0);
}

// DPP ring reductions over the 16-lane row (pure VALU, no DS latency).
template <int CTRL>
__device__ __forceinline__ float dpp_ror(float x) {
    int r = __builtin_amdgcn_update_dpp(
        0, __builtin_bit_cast(int, x), CTRL, 0xF, 0xF, true);
    return __builtin_bit_cast(float, r);
}
__device__ __forceinline__ float rmax16(float x) {
    x = fmaxf(x, dpp_ror<0x128>(x));   // row_ror:8
    x = fmaxf(x, dpp_ror<0x124>(x));   // row_ror:4
    x = fmaxf(x, dpp_ror<0x122>(x));   // row_ror:2
    x = fmaxf(x, dpp_ror<0x121>(x));   // row_ror:1
    return x;
}
__device__ __forceinline__ float rsum16(float x) {
    x += dpp_ror<0x128>(x);
    x += dpp_ror<0x124>(x);
    x += dpp_ror<0x122>(x);
    x += dpp_ror<0x121>(x);
    return x;
}

// ---------------- Stage 1: fused QKV projection (fp32 in, f16 out) ------
// v12 (kept): raw-barrier pipelined staging, LDS double-buffer, register
// ping-pong, ONE barrier per K-tile, counted waits.
// q: natural [row][e]. k: swizzled rows — element (s,e) at s*512 + ((e/8)^(s&7))*8 + e%8.
// v: chunked+swizzled [b][kc][e][64]: (d,s) at ((b*64+kc)*512+d)*64 + (((s&63)/8)^(d&7))*8 + s%8.
__global__ __launch_bounds__(256, 2) void proj_kernel(
    const float* __restrict__ Xq, const float* __restrict__ Xk,
    const float* __restrict__ Xv,
    const float* __restrict__ Wq, const float* __restrict__ Wk,
    const float* __restrict__ Wv,
    const float* __restrict__ bq, const float* __restrict__ bk,
    const float* __restrict__ bv,
    _Float16* __restrict__ oq, _Float16* __restrict__ ok,
    _Float16* __restrict__ ovt, int b0)
{
    __shared__ __align__(16) _Float16 As[2][128 * 32];
    __shared__ __align__(16) _Float16 Bs[2][128 * 32];
    const int t = threadIdx.x;
    const int w = t >> 6, ln = t & 63;
    const int which = blockIdx.y;
    const float* X    = (which == 0) ? Xq : ((which == 1) ? Xk : Xv);
    const float* W    = (which == 0) ? Wq : ((which == 1) ? Wk : Wv);
    const float* bias = (which == 0) ? bq : ((which == 1) ? bk : bv);

    const int m0 = (blockIdx.x >> 2) * 128;
    const int n0 = (blockIdx.x & 3) * 128;

    const int srow  = t >> 1;
    const int shalf = (t & 1) * 16;
    const float* gA = X + ((size_t)b0 * NS + m0 + srow) * NE + shalf;
    const float* gB = W + (size_t)(n0 + srow) * NE + shalf;

    f32x4 acc[4][4] = {};
    const int wm = (w >> 1) * 64, wn = (w & 1) * 64;
    const int lcol = ln & 15, lq = ln >> 4;

    float4 ra[4], rb[4], na[4], nb[4];

    auto LOAD = [&](int k0, float4* da, float4* db) {
        da[0] = *(const float4*)(gA + k0);
        da[1] = *(const float4*)(gA + k0 + 4);
        da[2] = *(const float4*)(gA + k0 + 8);
        da[3] = *(const float4*)(gA + k0 + 12);
        db[0] = *(const float4*)(gB + k0);
        db[1] = *(const float4*)(gB + k0 + 4);
        db[2] = *(const float4*)(gB + k0 + 8);
        db[3] = *(const float4*)(gB + k0 + 12);
    };
    auto WRITE = [&](int p, const float4* da, const float4* db) {
        *(f16x8*)&As[p][srow * 32 + shalf]     = cvt2(da[0], da[1]);
        *(f16x8*)&As[p][srow * 32 + shalf + 8] = cvt2(da[2], da[3]);
        *(f16x8*)&Bs[p][srow * 32 + shalf]     = cvt2(db[0], db[1]);
        *(f16x8*)&Bs[p][srow * 32 + shalf + 8] = cvt2(db[2], db[3]);
    };
    auto COMPUTE = [&](int p) {
        f16x8 a[4], b[4];
#pragma unroll
        for (int i = 0; i < 4; i++)
            a[i] = *(const f16x8*)&As[p][(wm + i * 16 + lcol) * 32 + lq * 8];
#pragma unroll
        for (int j = 0; j < 4; j++)
            b[j] = *(const f16x8*)&Bs[p][(wn + j * 16 + lcol) * 32 + lq * 8];
#pragma unroll
        for (int i = 0; i < 4; i++)
#pragma unroll
            for (int j = 0; j < 4; j++)
                acc[i][j] = __builtin_amdgcn_mfma_f32_16x16x32_f16(a[i], b[j], acc[i][j], 0, 0, 0);
    };

    // prologue: tile0 -> buf0, tile1 -> na (in flight)
    LOAD(0, ra, rb);
    asm volatile("s_waitcnt vmcnt(0)" ::: "memory");
    WRITE(0, ra, rb);
    LOAD(32, na, nb);
    asm volatile("s_waitcnt lgkmcnt(0)" ::: "memory");
    __builtin_amdgcn_s_barrier();                   // buf0 visible
    asm volatile("" ::: "memory");

#pragma unroll
    for (int kk = 0; kk < 8; kk++) {
        // ---- tile 2kk from buf0; stage 2kk+1 (na) -> buf1; load 2kk+2 -> ra
        COMPUTE(0);
        asm volatile("s_waitcnt vmcnt(0)" ::: "memory");   // na ready (hidden)
        WRITE(1, na, nb);
        if (2 * kk + 2 < 16) LOAD((2 * kk + 2) * 32, ra, rb);
        asm volatile("s_waitcnt lgkmcnt(0)" ::: "memory");
        __builtin_amdgcn_s_barrier();               // buf1 visible, buf0 free
        asm volatile("" ::: "memory");
        // ---- tile 2kk+1 from buf1; stage 2kk+2 (ra) -> buf0; load 2kk+3 -> na
        COMPUTE(1);
        if (2 * kk + 2 < 16) {
            asm volatile("s_waitcnt vmcnt(0)" ::: "memory");
            WRITE(0, ra, rb);
            if (2 * kk + 3 < 16) LOAD((2 * kk + 3) * 32, na, nb);
            asm volatile("s_waitcnt lgkmcnt(0)" ::: "memory");
            __builtin_amdgcn_s_barrier();           // buf0 visible, buf1 free
            asm volatile("" ::: "memory");
        }
    }

    // C/D layout: col = lane&15, row = (lane>>4)*4 + reg
    if (which == 0) {
#pragma unroll
        for (int j = 0; j < 4; j++) {
            const int col = n0 + wn + j * 16 + lcol;
            const float bb = bias[col];
#pragma unroll
            for (int i = 0; i < 4; i++) {
                const int rbase = m0 + wm + i * 16 + lq * 4;
#pragma unroll
                for (int r = 0; r < 4; r++)
                    oq[(size_t)(rbase + r) * NE + col] = (_Float16)(acc[i][j][r] + bb);
            }
        }
    } else if (which == 1) {
#pragma unroll
        for (int j = 0; j < 4; j++) {
            const int col = n0 + wn + j * 16 + lcol;
            const int cch = col >> 3, clo = col & 7;
            const float bb = bias[col];
#pragma unroll
            for (int i = 0; i < 4; i++) {
                const int rbase = m0 + wm + i * 16 + lq * 4;
#pragma unroll
                for (int r = 0; r < 4; r++) {
                    const int s = rbase + r;
                    ok[(size_t)s * NE + ((cch ^ (s & 7)) << 3) + clo] =
                        (_Float16)(acc[i][j][r] + bb);
                }
            }
        }
    } else {
#pragma unroll
        for (int j = 0; j < 4; j++) {
            const int d = n0 + wn + j * 16 + lcol;
            const float bb = bias[d];
#pragma unroll
            for (int i = 0; i < 4; i++) {
                const int rbase = m0 + wm + i * 16 + lq * 4;
                const int bat = rbase >> 12;
                const int sl  = rbase & 4095;
                const int kc  = sl >> 6;
                const int slot = ((sl >> 3) & 7) ^ (d & 7);
                f16x4 pk;
#pragma unroll
                for (int r = 0; r < 4; r++) pk[r] = (_Float16)(acc[i][j][r] + bb);
                *(f16x4*)&ovt[(((size_t)bat * 64 + kc) * NE + d) * 64 + slot * 8 + (sl & 7)] = pk;
            }
        }
    }
}

// ---------------- Stage 2: flash attention v14 --------------------------
// v10 skeleton (KB=64, 8 waves, 64 iters, split staging, counted vmcnt,
// DPP softmax, folded-max) with a 2x V-dedup PV split that FITS the
// register file (v13's 4x dedup spilled: ~264 regs > 256):
//   PV wave tile = 32 rows x 128 E-cols. rh = rt>>1 (home QK tile stays
//   inside the PV row-half -> m_home fold stays register-local);
//   eh = (w&1) | ((w>>2)<<1) picks the E-quarter. V fragments loaded once
//   per et, reused across the 2 row-tiles: V LDS reads 256->128 KB/iter.
// Budget: qf 64 + pa 32 + V 16 + state 28 + misc ~20 = ~160 arch + 64 acc.
// QK unchanged: wave (rt=w&3, g=w>>2): rows rt*16.., keys g*32..
__global__ __launch_bounds__(512, 2) void attn_kernel(
    const _Float16* __restrict__ q, const _Float16* __restrict__ ksw,
    const _Float16* __restrict__ vsw, float* __restrict__ out, int b0)
{
    __shared__ __align__(16) _Float16 Kb[64 * 512];
    __shared__ __align__(16) _Float16 Vb[512 * 64];
    __shared__ __align__(16) _Float16 Pb[64 * 72];
    __shared__ float mpart[2][64];
    __shared__ float lpart[2][64];

    const int t = threadIdx.x, w = t >> 6, ln = t & 63;
    const int lcol = ln & 15, lq = ln >> 4;
    const int rt = w & 3, g = w >> 2;
    const int rh = rt >> 1;                        // PV row-half (contains rt)
    const int eh = (w & 1) | ((w >> 2) << 1);      // PV E-quarter 0..3
    const int qh_home = rt & 1;                    // home tile within row-half
    const int xm = lcol & 7;

    // XCD-aware swizzle (proven: FETCH 139->41 MB): 2 XCDs per batch
    int qx, rel;
    if (gridDim.y == 4) {
        const int id = blockIdx.x + (blockIdx.y << 6);   // 0..255, hw xcd = id&7
        const int xcd = id & 7, slot = id >> 3;          // slot 0..31
        rel = xcd >> 1;
        qx  = ((xcd & 1) << 5) + slot;
    } else { qx = blockIdx.x; rel = blockIdx.y; }
    const int babs = b0 + rel;
    const int q0 = qx * 64;

    const _Float16* qp = q + ((size_t)rel * NS + q0 + rt * 16 + lcol) * NE + lq * 8;
    f16x8 qf[16];
#pragma unroll
    for (int ks = 0; ks < 16; ks++) qf[ks] = *(const f16x8*)(qp + ks * 32);

    const _Float16* kbase = ksw + (size_t)rel * NS * NE;
    const _Float16* vbase = vsw + (size_t)rel * NS * NE;

    auto stageK = [&](int kc) {
        const _Float16* src = kbase + (size_t)kc * 64 * NE;
#pragma unroll
        for (int i = 0; i < 8; i++) {
            const int blk = i * 8 + w;                   // 1 KB block index
            gload_lds16(src + (size_t)blk * 512 + ln * 8, (_Float16*)Kb + blk * 512);
        }
    };
    auto stageV = [&](int kc) {
        const _Float16* src = vbase + (size_t)kc * NE * 64;
#pragma unroll
        for (int i = 0; i < 8; i++) {
            const int blk = i * 8 + w;
            gload_lds16(src + (size_t)blk * 512 + ln * 8, (_Float16*)Vb + blk * 512);
        }
    };

    // oacc[qt][et]: row-tile rh*2+qt, E-col eh*128 + et*16
    f32x4 oacc[2][8] = {};
    float m_st[2][4], l_st[2][4];
#pragma unroll
    for (int qt = 0; qt < 2; qt++)
#pragma unroll
        for (int r = 0; r < 4; r++) { m_st[qt][r] = -1e30f; l_st[qt][r] = 0.f; }
    float m_home[4] = {-1e30f, -1e30f, -1e30f, -1e30f};  // = m_st[qh_home][*]

    asm volatile("" ::: "memory");
    stageK(0);
    stageV(0);

    for (int kc = 0; kc < 64; kc++) {
        // K(t) done (V(t) / K(t+1) stay in flight); then cross-wave sync
        asm volatile("s_waitcnt vmcnt(8)" ::: "memory");
        __builtin_amdgcn_s_barrier();                    // A: K(t) visible
        asm volatile("" ::: "memory");

        // ---- QK^T: 16 q-rows x 32 keys (keys g*32..+32), K=512
        f32x4 s0 = {}, s1 = {};
        __builtin_amdgcn_s_setprio(1);
#pragma unroll
        for (int ks = 0; ks < 16; ks++) {
            const int ch = ((ks * 4 + lq) ^ xm) * 8;
            f16x8 kb0 = *(const f16x8*)&Kb[(g * 32 + lcol) * 512 + ch];
            f16x8 kb1 = *(const f16x8*)&Kb[(g * 32 + 16 + lcol) * 512 + ch];
            s0 = __builtin_amdgcn_mfma_f32_16x16x32_f16(qf[ks], kb0, s0, 0, 0, 0);
            s1 = __builtin_amdgcn_mfma_f32_16x16x32_f16(qf[ks], kb1, s1, 0, 0, 0);
        }
        __builtin_amdgcn_s_setprio(0);

        asm volatile("" ::: "memory");
        __builtin_amdgcn_s_barrier();                    // B: Kb free
        asm volatile("" ::: "memory");
        if (kc < 63) stageK(kc + 1);                     // overlaps softmax+PV

        // ---- wave-local folded softmax (home rows rt*16 + lq*4+r)
#pragma unroll
        for (int r = 0; r < 4; r++) {
            float mx = rmax16(fmaxf(s0[r], s1[r]));
            const float mg = fmaxf(m_home[r], mx);
            const float p0 = __expf(s0[r] - mg);
            const float p1 = __expf(s1[r] - mg);
            const int row = rt * 16 + lq * 4 + r;
            Pb[row * 72 + g * 32 + lcol]      = (_Float16)p0;
            Pb[row * 72 + g * 32 + 16 + lcol] = (_Float16)p1;
            const float ls = rsum16(p0 + p1);
            if (lcol == 0) { mpart[g][row] = mg; lpart[g][row] = ls; }
        }

        // V(t) done + own P/partial writes visible; then sync
        if (kc < 63) { asm volatile("s_waitcnt vmcnt(8) lgkmcnt(0)" ::: "memory"); }
        else         { asm volatile("s_waitcnt vmcnt(0) lgkmcnt(0)" ::: "memory"); }
        __builtin_amdgcn_s_barrier();                    // C: V(t), P, partials
        asm volatile("" ::: "memory");

        // ---- combine halves for the wave's 8 thread-rows (2 tiles x 4)
        float alpha[2][4];
        bool allone = true;
#pragma unroll
        for (int qt = 0; qt < 2; qt++) {
#pragma unroll
            for (int r = 0; r < 4; r++) {
                const int row = (rh * 2 + qt) * 16 + lq * 4 + r;
                const float M0 = mpart[0][row], M1 = mpart[1][row];
                const float mn = fmaxf(M0, M1);
                const float a = __expf(m_st[qt][r] - mn);
                l_st[qt][r] = l_st[qt][r] * a
                            + __expf(M0 - mn) * lpart[0][row]
                            + __expf(M1 - mn) * lpart[1][row];
                m_st[qt][r] = mn;
                if (qt == qh_home) m_home[r] = mn;       // static idx, predicated
                alpha[qt][r] = a;
                allone = allone & (a == 1.f);
            }
        }
        if (!__all(allone)) {
#pragma unroll
            for (int qt = 0; qt < 2; qt++)
#pragma unroll
                for (int et = 0; et < 8; et++) {
                    oacc[qt][et][0] *= alpha[qt][0];
                    oacc[qt][et][1] *= alpha[qt][1];
                    oacc[qt][et][2] *= alpha[qt][2];
                    oacc[qt][et][3] *= alpha[qt][3];
                }
        }

        // ---- P A-fragments for the 2 row-tiles (rows = lcol within tile)
        // pa0 = keys 0..31 (g=0 wave), pa1 = keys 32..63 (g=1 wave);
        // per-half correction exp(Mg - mn) exactly as v10.
        f16x8 pa0[2], pa1[2];
#pragma unroll
        for (int qt = 0; qt < 2; qt++) {
            const int frow = (rh * 2 + qt) * 16 + lcol;
            const float F0 = mpart[0][frow], F1 = mpart[1][frow];
            const float fm = fmaxf(F0, F1);
            const _Float16 c0 = (_Float16)__expf(F0 - fm);
            const _Float16 c1 = (_Float16)__expf(F1 - fm);
            pa0[qt] = *(const f16x8*)&Pb[frow * 72 + lq * 8];
            pa1[qt] = *(const f16x8*)&Pb[frow * 72 + 32 + lq * 8];
#pragma unroll
            for (int j = 0; j < 8; j++) { pa0[qt][j] *= c0; pa1[qt][j] *= c1; }
        }

        // ---- PV: rows (rh*2..+2 tiles), E-cols eh*128..+128, K=64.
        // V fragment loaded once per et, reused across both row-tiles.
        __builtin_amdgcn_s_setprio(1);
#pragma unroll
        for (int et = 0; et < 8; et++) {
            const int e = eh * 128 + et * 16 + lcol;
            f16x8 v0 = *(const f16x8*)&Vb[e * 64 + ((lq ^ xm) * 8)];
            f16x8 v1 = *(const f16x8*)&Vb[e * 64 + (((4 + lq) ^ xm) * 8)];
            oacc[0][et] = __builtin_amdgcn_mfma_f32_16x16x32_f16(pa0[0], v0, oacc[0][et], 0, 0, 0);
            oacc[0][et] = __builtin_amdgcn_mfma_f32_16x16x32_f16(pa1[0], v1, oacc[0][et], 0, 0, 0);
            oacc[1][et] = __builtin_amdgcn_mfma_f32_16x16x32_f16(pa0[1], v0, oacc[1][et], 0, 0, 0);
            oacc[1][et] = __builtin_amdgcn_mfma_f32_16x16x32_f16(pa1[1], v1, oacc[1][et], 0, 0, 0);
        }
        __builtin_amdgcn_s_setprio(0);

        asm volatile("" ::: "memory");
        __builtin_amdgcn_s_barrier();                    // D: Vb, Pb free
        asm volatile("" ::: "memory");
        if (kc < 63) stageV(kc + 1);                     // overlaps next QK
    }

    // ---- epilogue: rows (rh*2+qt)*16.., E-cols eh*128..+128
#pragma unroll
    for (int qt = 0; qt < 2; qt++)
#pragma unroll
        for (int r = 0; r < 4; r++) {
            const float inv = 1.0f / l_st[qt][r];
            const size_t ob = ((size_t)babs * NS + q0 + (rh * 2 + qt) * 16 + lq * 4 + r) * NE
                            + eh * 128 + lcol;
#pragma unroll
            for (int et = 0; et < 8; et++)
                out[ob + et * 16] = oacc[qt][et][r] * inv;
        }
}

extern "C" void kernel_launch(void* const* d_in, const int* in_sizes, int n_in,
                              void* d_out, int out_size, void* d_ws, size_t ws_size,
                              hipStream_t stream) {
    const float* query = (const float*)d_in[0];
    const float* key_  = (const float*)d_in[1];
    const float* value = (const float*)d_in[2];
    const float* Wq    = (const float*)d_in[3];
    const float* bq    = (const float*)d_in[4];
    const float* Wk    = (const float*)d_in[5];
    const float* bk    = (const float*)d_in[6];
    const float* Wv    = (const float*)d_in[7];
    const float* bv    = (const float*)d_in[8];

    const size_t per_batch = (size_t)3 * NS * NE * 2;   // q + k_sw + v_sw f16 = 12 MiB
    int nb_chunk = (int)(ws_size / per_batch);
    if (nb_chunk > NB) nb_chunk = NB;
    if (nb_chunk < 1)  nb_chunk = 1;

    _Float16* qh  = (_Float16*)d_ws;
    _Float16* kh  = qh + (size_t)nb_chunk * NS * NE;
    _Float16* vth = kh + (size_t)nb_chunk * NS * NE;

    for (int b0 = 0; b0 < NB; b0 += nb_chunk) {
        int nb = NB - b0 < nb_chunk ? NB - b0 : nb_chunk;
        proj_kernel<<<dim3(nb * 128, 3, 1), 256, 0, stream>>>(
            query, key_, value, Wq, Wk, Wv, bq, bk, bv, qh, kh, vth, b0);
        attn_kernel<<<dim3(NS / 64, nb, 1), 512, 0, stream>>>(
            qh, kh, vth, (float*)d_out, b0);
    }
}